// Round 1
// 151.847 us; speedup vs baseline: 1.0318x; 1.0318x over previous
//
#include <hip/hip_runtime.h>
#include <hip/hip_bf16.h>

#define B_  2
#define S_  512
#define H_  8
#define D_  32
#define DM_ 256
#define HD_ 256
#define NROW 4

// ---------------------------------------------------------------------------
// Kernel A: QKV projection.  grid = (B*S/NROW, 3), block = 256.
// out layout: (b, h, s, d).  q is pre-scaled by 1/sqrt(D).
// ---------------------------------------------------------------------------
__global__ __launch_bounds__(256) void qkv_kernel(
    const float* __restrict__ hid, const float* __restrict__ wq,
    const float* __restrict__ wk, const float* __restrict__ wv,
    float* __restrict__ qo, float* __restrict__ ko, float* __restrict__ vo)
{
  __shared__ __align__(16) float hs[NROW][DM_];
  const int r0 = blockIdx.x * NROW;                 // global row in [0, B*S)
  const float* w   = (blockIdx.y == 0) ? wq : (blockIdx.y == 1) ? wk : wv;
  float*       out = (blockIdx.y == 0) ? qo : (blockIdx.y == 1) ? ko : vo;
  const float mulf = (blockIdx.y == 0) ? 0.17677669529663687f : 1.0f;
  const int tid = threadIdx.x;

  for (int idx = tid; idx < NROW * DM_; idx += 256)
    hs[idx >> 8][idx & 255] = hid[r0 * DM_ + idx];
  __syncthreads();

  float acc[NROW] = {0.f, 0.f, 0.f, 0.f};
  const float* wp = w + tid;                        // column m = tid
  #pragma unroll 8
  for (int c4 = 0; c4 < DM_ / 4; ++c4) {
    const float w0 = wp[(4 * c4 + 0) * HD_];
    const float w1 = wp[(4 * c4 + 1) * HD_];
    const float w2 = wp[(4 * c4 + 2) * HD_];
    const float w3 = wp[(4 * c4 + 3) * HD_];
    #pragma unroll
    for (int r = 0; r < NROW; ++r) {
      const float4 hv = reinterpret_cast<const float4*>(&hs[r][0])[c4];
      acc[r] = fmaf(hv.x, w0, acc[r]);
      acc[r] = fmaf(hv.y, w1, acc[r]);
      acc[r] = fmaf(hv.z, w2, acc[r]);
      acc[r] = fmaf(hv.w, w3, acc[r]);
    }
  }
  const int h = tid >> 5, d = tid & 31;
  #pragma unroll
  for (int r = 0; r < NROW; ++r) {
    const int g = r0 + r;
    const int b = g >> 9, s = g & (S_ - 1);
    out[((b * H_ + h) * S_ + s) * D_ + d] = acc[r] * mulf;
  }
}

// 4-lane (quad) butterfly sum via DPP: all 4 lanes of the quad get the sum.
__device__ __forceinline__ float red4(float x) {
  int i;
  i = __builtin_amdgcn_mov_dpp(__float_as_int(x), 0xB1, 0xf, 0xf, true); // quad_perm xor1
  x += __int_as_float(i);
  i = __builtin_amdgcn_mov_dpp(__float_as_int(x), 0x4E, 0xf, 0xf, true); // quad_perm xor2
  x += __int_as_float(i);
  return x;
}

// ---------------------------------------------------------------------------
// Kernel B (fused): scores + mask + softmax + attn@V + fc + residual + LN.
// One block per (b, i): grid = B*S = 1024, block = 256 (4 waves), 4 blocks/CU.
// All 8 heads handled per block -> rpe row (b,i,:,:) read EXACTLY ONCE from
// L2 (was 4x with HC=2), and the fc/LN epilogue consumes the o-row straight
// from LDS: no o_ws round-trip, one fewer kernel launch.
// K for row i lives in LDS (1 KB) instead of 64 VGPRs -> fits 128-reg budget.
// Score mapping: lane=(j4,dq), 4 dq-lanes cover one j's 128B d-row (32B each).
// attn@V mapping: lane=(j8,dc), dc*16B slice.
// scores[h,j] = sum_d q'[h,j,d] k[h,i,d] rpe[i,j,d]  (q' pre-scaled);
// mask: j < station OR j == i.
// NOTE: register arrays use compile-time indices ONLY (dynamic index ->
// scratch demotion -> spill traffic).
// ---------------------------------------------------------------------------
__global__ __launch_bounds__(256, 4) void attn_fused_kernel(
    const float* __restrict__ rpe, const float* __restrict__ q_ws,
    const float* __restrict__ k_ws, const float* __restrict__ v_ws,
    const int* __restrict__ station_p, const float* __restrict__ fc_w,
    const float* __restrict__ fc_b, const float* __restrict__ hid,
    const float* __restrict__ ln_w, const float* __restrict__ ln_b,
    float* __restrict__ out)
{
  __shared__ __align__(16) float p_smem[H_ * S_];   // 16 KB; reused as redv
  __shared__ __align__(16) float ks[H_ * D_];       // 1 KB K row, 8 heads
  __shared__ __align__(16) float orow[HD_];         // 1 KB attention output row
  __shared__ float sums[H_];
  __shared__ float redm[4];
  __shared__ float redvr[4];

  const int tid  = threadIdx.x;
  const int w    = tid >> 6, lane = tid & 63;
  const int j4   = lane >> 2, dq = lane & 3;        // score mapping
  const int j8   = lane >> 3, dc = lane & 7;        // attn@V mapping
  const int n    = blockIdx.x;                      // 0..1023
  const int b    = n >> 9;
  const int i    = n & (S_ - 1);
  const int HS   = S_ * D_;                         // head stride

  int station = station_p[0];
  station = station > S_ ? S_ : (station < 0 ? 0 : station);

  const float* qb = q_ws + (size_t)(b * H_) * S_ * D_;
  const float* kb = k_ws + (size_t)(b * H_) * S_ * D_;
  const float* vb = v_ws + (size_t)(b * H_) * S_ * D_;
  const float* rb = rpe + ((size_t)b * S_ + i) * S_ * D_;

  // stage K row i for all 8 heads into LDS
  {
    const int h = tid >> 5, d = tid & 31;
    ks[tid] = kb[h * HS + i * D_ + d];
  }
  __syncthreads();

  // ---- scores: wave w covers j in {w*16 + pass*64 + j4} ----
  for (int jb = w * 16; jb < station; jb += 64) {
    const int j  = jb + j4;
    const int jc = j < S_ ? j : S_ - 1;
    const float4 r0 = *reinterpret_cast<const float4*>(rb + jc * D_ + dq * 8);
    const float4 r1 = *reinterpret_cast<const float4*>(rb + jc * D_ + dq * 8 + 4);
    #pragma unroll
    for (int hh = 0; hh < H_; ++hh) {
      const float4 q0 = *reinterpret_cast<const float4*>(qb + hh * HS + jc * D_ + dq * 8);
      const float4 q1 = *reinterpret_cast<const float4*>(qb + hh * HS + jc * D_ + dq * 8 + 4);
      const float4 k0 = *reinterpret_cast<const float4*>(&ks[hh * D_ + dq * 8]);
      const float4 k1 = *reinterpret_cast<const float4*>(&ks[hh * D_ + dq * 8 + 4]);
      float s = q0.x * k0.x * r0.x;
      s = fmaf(q0.y * k0.y, r0.y, s);
      s = fmaf(q0.z * k0.z, r0.z, s);
      s = fmaf(q0.w * k0.w, r0.w, s);
      s = fmaf(q1.x * k1.x, r1.x, s);
      s = fmaf(q1.y * k1.y, r1.y, s);
      s = fmaf(q1.z * k1.z, r1.z, s);
      s = fmaf(q1.w * k1.w, r1.w, s);
      s = red4(s);
      if (dq == 0 && j < station) p_smem[hh * S_ + j] = s;
    }
  }
  // diagonal cell j == i when i >= station (wave 0, lanes 0..3 = one quad)
  if (w == 0 && j4 == 0 && i >= station) {
    const float4 r0 = *reinterpret_cast<const float4*>(rb + i * D_ + dq * 8);
    const float4 r1 = *reinterpret_cast<const float4*>(rb + i * D_ + dq * 8 + 4);
    #pragma unroll
    for (int hh = 0; hh < H_; ++hh) {
      const float4 q0 = *reinterpret_cast<const float4*>(qb + hh * HS + i * D_ + dq * 8);
      const float4 q1 = *reinterpret_cast<const float4*>(qb + hh * HS + i * D_ + dq * 8 + 4);
      const float4 k0 = *reinterpret_cast<const float4*>(&ks[hh * D_ + dq * 8]);
      const float4 k1 = *reinterpret_cast<const float4*>(&ks[hh * D_ + dq * 8 + 4]);
      float s = q0.x * k0.x * r0.x;
      s = fmaf(q0.y * k0.y, r0.y, s);
      s = fmaf(q0.z * k0.z, r0.z, s);
      s = fmaf(q0.w * k0.w, r0.w, s);
      s = fmaf(q1.x * k1.x, r1.x, s);
      s = fmaf(q1.y * k1.y, r1.y, s);
      s = fmaf(q1.z * k1.z, r1.z, s);
      s = fmaf(q1.w * k1.w, r1.w, s);
      s = red4(s);
      if (dq == 0) p_smem[hh * S_ + i] = s;
    }
  }
  __syncthreads();

  // ---- softmax: wave w handles head rows w and w+4 ----
  const bool dx = (i >= station);
  #pragma unroll
  for (int rr = 0; rr < 2; ++rr) {
    const int r = w + rr * 4;
    float m = -1e30f;
    for (int jj = lane; jj < station; jj += 64) m = fmaxf(m, p_smem[r * S_ + jj]);
    const float dv = dx ? p_smem[r * S_ + i] : -1e30f;
    m = fmaxf(m, dv);
    #pragma unroll
    for (int o = 32; o; o >>= 1) m = fmaxf(m, __shfl_xor(m, o, 64));
    float sum = 0.f;
    for (int jj = lane; jj < station; jj += 64) {
      const float e = __expf(p_smem[r * S_ + jj] - m);
      p_smem[r * S_ + jj] = e;
      sum += e;
    }
    #pragma unroll
    for (int o = 32; o; o >>= 1) sum += __shfl_xor(sum, o, 64);
    if (dx) {
      const float e = __expf(dv - m);
      sum += e;
      if (lane == 0) p_smem[r * S_ + i] = e;
    }
    if (lane == 0) sums[r] = sum;
  }
  __syncthreads();

  // ---- attn @ V: thread (j8,dc) accumulates its j-slice, all 8 heads ----
  float4 acc[H_];
  #pragma unroll
  for (int hh = 0; hh < H_; ++hh) acc[hh] = make_float4(0.f, 0.f, 0.f, 0.f);

  for (int jb = w * 8; jb < station; jb += 32) {
    const int j  = jb + j8;
    const int jc = j < S_ ? j : S_ - 1;
    #pragma unroll
    for (int hh = 0; hh < H_; ++hh) {
      const float4 v4 = *reinterpret_cast<const float4*>(vb + hh * HS + jc * D_ + dc * 4);
      float pv = 0.f;
      if (j < station) pv = p_smem[hh * S_ + j];
      acc[hh].x = fmaf(pv, v4.x, acc[hh].x);
      acc[hh].y = fmaf(pv, v4.y, acc[hh].y);
      acc[hh].z = fmaf(pv, v4.z, acc[hh].z);
      acc[hh].w = fmaf(pv, v4.w, acc[hh].w);
    }
  }
  // diagonal contribution (exactly once: wave 0, j8==0 lanes)
  if (w == 0 && j8 == 0 && dx) {
    #pragma unroll
    for (int hh = 0; hh < H_; ++hh) {
      const float pv = p_smem[hh * S_ + i];
      const float4 v4 = *reinterpret_cast<const float4*>(vb + hh * HS + i * D_ + dc * 4);
      acc[hh].x = fmaf(pv, v4.x, acc[hh].x);
      acc[hh].y = fmaf(pv, v4.y, acc[hh].y);
      acc[hh].z = fmaf(pv, v4.z, acc[hh].z);
      acc[hh].w = fmaf(pv, v4.w, acc[hh].w);
    }
  }
  __syncthreads();   // p_smem reads done before reuse as redv

  // ---- reduce over (w, j8): shfl over j8 bits then LDS over waves ----
  float4* redv = reinterpret_cast<float4*>(p_smem);   // 4 waves x 8 heads x 8 dc
  #pragma unroll
  for (int hh = 0; hh < H_; ++hh) {
    float4 a = acc[hh];
    #pragma unroll
    for (int o = 8; o <= 32; o <<= 1) {
      a.x += __shfl_xor(a.x, o, 64);
      a.y += __shfl_xor(a.y, o, 64);
      a.z += __shfl_xor(a.z, o, 64);
      a.w += __shfl_xor(a.w, o, 64);
    }
    if (j8 == 0) redv[(w * H_ + hh) * 8 + dc] = a;
  }
  __syncthreads();
  if (tid < H_ * 8) {
    const int r = tid >> 3, d4 = tid & 7;             // r = head
    float4 a = make_float4(0.f, 0.f, 0.f, 0.f);
    #pragma unroll
    for (int g = 0; g < 4; ++g) {
      const float4 x = redv[(g * H_ + r) * 8 + d4];
      a.x += x.x; a.y += x.y; a.z += x.z; a.w += x.w;
    }
    const float inv = 1.f / sums[r];
    orow[r * D_ + d4 * 4 + 0] = a.x * inv;
    orow[r * D_ + d4 * 4 + 1] = a.y * inv;
    orow[r * D_ + d4 * 4 + 2] = a.z * inv;
    orow[r * D_ + d4 * 4 + 3] = a.w * inv;
  }
  __syncthreads();

  // ---- fc (thread per output column m=tid) + bias + residual + LN ----
  float fca = 0.f;
  const float* wp = fc_w + tid;
  #pragma unroll 8
  for (int n4 = 0; n4 < HD_ / 4; ++n4) {
    const float4 ov = reinterpret_cast<const float4*>(orow)[n4];
    fca = fmaf(ov.x, wp[(4 * n4 + 0) * DM_], fca);
    fca = fmaf(ov.y, wp[(4 * n4 + 1) * DM_], fca);
    fca = fmaf(ov.z, wp[(4 * n4 + 2) * DM_], fca);
    fca = fmaf(ov.w, wp[(4 * n4 + 3) * DM_], fca);
  }
  fca += fc_b[tid] + hid[(size_t)n * DM_ + tid];

  // mean
  {
    float s = fca;
    #pragma unroll
    for (int o = 32; o; o >>= 1) s += __shfl_xor(s, o, 64);
    if (lane == 0) redm[w] = s;
  }
  __syncthreads();
  const float mu = (redm[0] + redm[1] + redm[2] + redm[3]) * (1.f / DM_);
  const float dd = fca - mu;
  {
    float s = dd * dd;
    #pragma unroll
    for (int o = 32; o; o >>= 1) s += __shfl_xor(s, o, 64);
    if (lane == 0) redvr[w] = s;
  }
  __syncthreads();
  const float var = (redvr[0] + redvr[1] + redvr[2] + redvr[3]) * (1.f / DM_);
  out[(size_t)n * DM_ + tid] = dd * rsqrtf(var + 1e-6f) * ln_w[tid] + ln_b[tid];
}

// ---------------------------------------------------------------------------
extern "C" void kernel_launch(void* const* d_in, const int* in_sizes, int n_in,
                              void* d_out, int out_size, void* d_ws, size_t ws_size,
                              hipStream_t stream) {
  const float* hid = (const float*)d_in[0];
  const float* rpe = (const float*)d_in[1];
  const float* wq  = (const float*)d_in[2];
  const float* wk  = (const float*)d_in[3];
  const float* wv  = (const float*)d_in[4];
  const float* fcw = (const float*)d_in[5];
  const float* fcb = (const float*)d_in[6];
  const float* lnw = (const float*)d_in[7];
  const float* lnb = (const float*)d_in[8];
  const int* station = (const int*)d_in[9];
  float* out = (float*)d_out;

  const size_t per = (size_t)B_ * H_ * S_ * D_;   // 262144 floats
  float* q_ws = (float*)d_ws;
  float* k_ws = q_ws + per;
  float* v_ws = k_ws + per;

  dim3 gA(B_ * S_ / NROW, 3);
  qkv_kernel<<<gA, 256, 0, stream>>>(hid, wq, wk, wv, q_ws, k_ws, v_ws);
  attn_fused_kernel<<<B_ * S_, 256, 0, stream>>>(
      rpe, q_ws, k_ws, v_ws, station, fcw, fcb, hid, lnw, lnb, out);
}